// Round 6
// baseline (460.552 us; speedup 1.0000x reference)
//
#include <hip/hip_runtime.h>
#include <math.h>

#define S_LEN 1024
#define DMODEL 1024
#define NH 16
#define HD 64
#define P2 512
#define BATCH 4

typedef unsigned short u16;
typedef __attribute__((ext_vector_type(8))) short short8;
typedef __attribute__((ext_vector_type(4))) float floatx4;

__device__ __forceinline__ u16 f2bf(float f) {
  unsigned u = __float_as_uint(f);
  unsigned r = u + 0x7FFFu + ((u >> 16) & 1u);
  return (u16)(r >> 16);
}
__device__ __forceinline__ float bf2f(u16 v) {
  return __uint_as_float(((unsigned)v) << 16);
}
__device__ __forceinline__ unsigned pk2bf(float a, float b) {
#if __has_builtin(__builtin_amdgcn_cvt_pk_bf16_f32)
  typedef __attribute__((ext_vector_type(2))) __bf16 bf2v;
  bf2v t = __builtin_amdgcn_cvt_pk_bf16_f32(a, b);
  return *(unsigned*)&t;
#else
  return (unsigned)f2bf(a) | ((unsigned)f2bf(b) << 16);
#endif
}
// async global->LDS, 16B per lane; lds dest = wave-uniform base + lane*16
__device__ __forceinline__ void gl_lds16(const void* g, void* l) {
  __builtin_amdgcn_global_load_lds(
      (const __attribute__((address_space(1))) void*)g,
      (__attribute__((address_space(3))) void*)l, 16, 0, 0);
}

// ---------------- prep: tab + concatenated bias ----------------
__global__ void prep_kernel(int* __restrict__ tab, const float* __restrict__ bq,
                            const float* __restrict__ bk, const float* __restrict__ bv,
                            float* __restrict__ biascat) {
  int t = blockIdx.x * blockDim.x + threadIdx.x;
  if (t < 2 * S_LEN - 1) {
    int rel = t - (S_LEN - 1);
    const int mid = 128;
    float abspos = (rel < mid && rel > -mid) ? (float)(mid - 1) : fabsf((float)rel);
    float bucket;
    if (abspos <= (float)mid) {
      bucket = (float)rel;
    } else {
      float den = (float)log(3.9921875);
      float lp = ceilf(logf(abspos / 128.0f) / den * 127.0f) + 128.0f;
      bucket = (rel > 0) ? lp : -lp;
    }
    int idx = (int)bucket + 256;
    idx = idx < 0 ? 0 : (idx > P2 - 1 ? P2 - 1 : idx);
    tab[t] = idx;
  }
  if (t < 3072) biascat[t] = t < 1024 ? bq[t] : (t < 2048 ? bk[t - 1024] : bv[t - 2048]);
}

// ---------------- single fused f32->bf16 cast over all inputs ----------------
__global__ __launch_bounds__(256) void cast_all(
    const float* __restrict__ h, const float* __restrict__ r,
    const float* __restrict__ wq, const float* __restrict__ wk,
    const float* __restrict__ wv, const float* __restrict__ wo,
    u16* __restrict__ hb, u16* __restrict__ rb,
    u16* __restrict__ wqkvb, u16* __restrict__ wob) {
  int b = blockIdx.x;
  const float* src;
  u16* dst;
  int off;
  if (b < 4096) { src = h; dst = hb; off = b; }
  else if (b < 4608) { src = r; dst = rb; off = b - 4096; }
  else if (b < 5632) { src = wq; dst = wqkvb; off = b - 4608; }
  else if (b < 6656) { src = wk; dst = wqkvb + 1024 * 1024; off = b - 5632; }
  else if (b < 7680) { src = wv; dst = wqkvb + 2 * 1024 * 1024; off = b - 6656; }
  else { src = wo; dst = wob; off = b - 7680; }
  long i = (long)off * 1024 + (threadIdx.x << 2);
  float4 v = *(const float4*)(src + i);
  uint2 o;
  o.x = pk2bf(v.x, v.y);
  o.y = pk2bf(v.z, v.w);
  *(uint2*)(dst + i) = o;
}

// ---------------- bf16 MFMA NT GEMM, 128x128 tile, BK=32 ----------------
// mode 0: f32 out + bias + resid (out-proj).  mode 1: bf16 row-major out + bias.
__global__ __launch_bounds__(256) void mgemm(
    const u16* __restrict__ A, const u16* __restrict__ Bw,
    const float* __restrict__ b0, const float* __restrict__ resid,
    void* out0, int M, int N, int K, int mode) {
  __shared__ u16 Al[128 * 32];
  __shared__ u16 Bl[128 * 32];
  const int tid = threadIdx.x;
  const int wave = tid >> 6, lane = tid & 63;
  const int quad = lane >> 4, l16 = lane & 15;
  const int m0 = blockIdx.y * 128, n0 = blockIdx.x * 128;

  const floatx4 fzero = {0.f, 0.f, 0.f, 0.f};
  floatx4 acc[4][4];
#pragma unroll
  for (int mi = 0; mi < 4; ++mi)
#pragma unroll
    for (int ni = 0; ni < 4; ++ni) acc[mi][ni] = fzero;

  const int wm = (wave & 1) * 64, wn = (wave >> 1) * 64;

  for (int k0 = 0; k0 < K; k0 += 32) {
#pragma unroll
    for (int i = 0; i < 2; ++i) {
      int ch = i * 256 + wave * 64 + lane;
      int row = ch >> 2, c = ch & 3;
      gl_lds16(A + (long)(m0 + row) * K + k0 + c * 8, Al + (i * 256 + wave * 64) * 8);
      gl_lds16(Bw + (long)(n0 + row) * K + k0 + c * 8, Bl + (i * 256 + wave * 64) * 8);
    }
    __syncthreads();
    short8 af[4], bf[4];
#pragma unroll
    for (int t = 0; t < 4; ++t) {
      af[t] = *(const short8*)(Al + (wm + t * 16 + l16) * 32 + quad * 8);
      bf[t] = *(const short8*)(Bl + (wn + t * 16 + l16) * 32 + quad * 8);
    }
#pragma unroll
    for (int mi = 0; mi < 4; ++mi)
#pragma unroll
      for (int ni = 0; ni < 4; ++ni)
        acc[mi][ni] =
            __builtin_amdgcn_mfma_f32_16x16x32_bf16(af[mi], bf[ni], acc[mi][ni], 0, 0, 0);
    __syncthreads();
  }

  if (mode == 0) {
    float* o = (float*)out0;
#pragma unroll
    for (int mi = 0; mi < 4; ++mi)
#pragma unroll
      for (int ni = 0; ni < 4; ++ni) {
        int n = n0 + wn + ni * 16 + l16;
#pragma unroll
        for (int r = 0; r < 4; ++r) {
          int m = m0 + wm + mi * 16 + quad * 4 + r;
          o[(long)m * N + n] = acc[mi][ni][r] + b0[n] + resid[(long)m * N + n];
        }
      }
  } else {
    u16* o = (u16*)out0;
#pragma unroll
    for (int mi = 0; mi < 4; ++mi)
#pragma unroll
      for (int ni = 0; ni < 4; ++ni) {
        int n = n0 + wn + ni * 16 + l16;
        float bias = b0[n];
        int mb = m0 + wm + mi * 16 + quad * 4;
#pragma unroll
        for (int r = 0; r < 4; ++r)
          o[(long)(mb + r) * N + n] = f2bf(acc[mi][ni][r] + bias);
      }
  }
}

// ---------------- V transpose: qkv_rm V-part -> Vt [B,H,64,S] ----------------
__global__ __launch_bounds__(256) void vtrans(const u16* __restrict__ qkv,
                                              u16* __restrict__ Vt) {
  __shared__ u16 tile[64][68];
  const int s0 = blockIdx.x * 64, h = blockIdx.y, b = blockIdx.z;
  const int t = threadIdx.x;
  const int r16 = t >> 4, c4 = (t & 15) << 2;
  const u16* src = qkv + ((long)(b * S_LEN + s0)) * 3072 + 2048 + h * HD;
#pragma unroll
  for (int i = 0; i < 4; ++i) {
    int row = i * 16 + r16;
    ushort4 v = *(const ushort4*)(src + (long)row * 3072 + c4);
    *(ushort4*)&tile[row][c4] = v;
  }
  __syncthreads();
  u16* dst = Vt + ((long)(b * NH + h) * HD) * S_LEN + s0;
#pragma unroll
  for (int i = 0; i < 4; ++i) {
    int dd = i * 16 + r16;
    ushort4 o;
    o.x = tile[c4 + 0][dd]; o.y = tile[c4 + 1][dd];
    o.z = tile[c4 + 2][dd]; o.w = tile[c4 + 3][dd];
    *(ushort4*)(dst + (long)dd * S_LEN + c4) = o;
  }
}

// ---------------- MFMA flash attention, v3 ----------------
// Q/K/V fragments read DIRECTLY from global (L2) — no LDS staging, 2 barriers/tile.
// Bias windows (adaptive, <=8 slices) recomputed on MFMA into CsT/DsT [col][row].
// Linear tiles (q0-k0 in {-64,0,64}): off = d - d_min arithmetically (no offL).
__global__ __launch_bounds__(256, 3) void flash_mfma(
    const u16* __restrict__ qkv, const u16* __restrict__ Vt,
    const u16* __restrict__ pos, const int* __restrict__ tab,
    u16* __restrict__ ctx, float sc2) {
  __shared__ u16 CsT[128 * 68];   // Gq^T [col][qloc]
  __shared__ u16 DsT[128 * 68];   // Gk^T [col][kloc]
  __shared__ u16 Ps[4][16 * 72];  // per-wave P strip [qloc16][kloc]
  __shared__ u16 offL[128];       // (tab[d]-base)*68

  const int tid = threadIdx.x;
  const int wave = tid >> 6, lane = tid & 63;
  const int quad = lane >> 4, l16 = lane & 15;
  const int h = blockIdx.y, q0 = blockIdx.x * 64;
  const int b = blockIdx.z;

  const u16* Qg = qkv + ((long)(b * S_LEN + q0)) * 3072 + h * HD;
  const u16* Kg = qkv + ((long)(b * S_LEN)) * 3072 + 1024 + h * HD;
  const u16* Vg = Vt + ((long)(b * NH + h) * HD) * S_LEN;
  const u16* posq_g = pos + h * HD;         // [512,2048] rows, Wq cols
  const u16* posk_g = pos + 1024 + h * HD;  // Wk cols

  // Q A-fragments straight from global (row-major qkv)
  short8 aq[4][2];
#pragma unroll
  for (int mi = 0; mi < 4; ++mi)
#pragma unroll
    for (int kk = 0; kk < 2; ++kk)
      aq[mi][kk] =
          *(const short8*)(Qg + (long)(mi * 16 + l16) * 3072 + kk * 32 + quad * 8);

  const floatx4 fzero = {0.f, 0.f, 0.f, 0.f};
  floatx4 acc[4];
#pragma unroll
  for (int ni = 0; ni < 4; ++ni) acc[ni] = fzero;
  float l_i[4] = {0.f, 0.f, 0.f, 0.f};

  u16* Pw = &Ps[wave][0];
  const int qb4 = wave * 16 + quad * 4;

  for (int k0 = 0; k0 < S_LEN; k0 += 64) {
    const int dmin = q0 - k0 - 63;
    const int base = tab[dmin + 1023];
    const int w = tab[dmin + 1023 + 126] - base + 1;  // monotone => >=1, <=127
    const int nsl = (w + 15) >> 4;
    const bool lin = (dmin >= -127) && (dmin <= 1);   // whole d-range linear
    if (!lin && tid < 127) offL[tid] = (u16)((tab[dmin + 1023 + tid] - base) * 68);

    // K fragments straight from global; identical layout serves Gk-A and QK-B
    short8 kf[4][2];
#pragma unroll
    for (int ni = 0; ni < 4; ++ni)
#pragma unroll
      for (int kk = 0; kk < 2; ++kk)
        kf[ni][kk] = *(const short8*)(Kg + (long)(k0 + ni * 16 + l16) * 3072 +
                                      kk * 32 + quad * 8);

    // ---- Gq slices (wave-strided) ----
    for (int sl = wave; sl < nsl; sl += 4) {
      floatx4 g[4];
#pragma unroll
      for (int mi = 0; mi < 4; ++mi) g[mi] = fzero;
      int wrow = base + sl * 16 + l16;
#pragma unroll
      for (int kk = 0; kk < 2; ++kk) {
        short8 bp = *(const short8*)(posk_g + (long)wrow * 2048 + kk * 32 + quad * 8);
#pragma unroll
        for (int mi = 0; mi < 4; ++mi)
          g[mi] = __builtin_amdgcn_mfma_f32_16x16x32_bf16(aq[mi][kk], bp, g[mi], 0, 0, 0);
      }
#pragma unroll
      for (int mi = 0; mi < 4; ++mi) {
        uint2 t;
        t.x = pk2bf(g[mi][0], g[mi][1]);
        t.y = pk2bf(g[mi][2], g[mi][3]);
        *(uint2*)(CsT + (sl * 16 + l16) * 68 + mi * 16 + quad * 4) = t;
      }
    }
    // ---- Gk slices ----
    for (int sl = wave; sl < nsl; sl += 4) {
      floatx4 g[4];
#pragma unroll
      for (int mi = 0; mi < 4; ++mi) g[mi] = fzero;
      int wrow = base + sl * 16 + l16;
#pragma unroll
      for (int kk = 0; kk < 2; ++kk) {
        short8 bp = *(const short8*)(posq_g + (long)wrow * 2048 + kk * 32 + quad * 8);
#pragma unroll
        for (int mi = 0; mi < 4; ++mi)
          g[mi] = __builtin_amdgcn_mfma_f32_16x16x32_bf16(kf[mi][kk], bp, g[mi], 0, 0, 0);
      }
#pragma unroll
      for (int mi = 0; mi < 4; ++mi) {
        uint2 t;
        t.x = pk2bf(g[mi][0], g[mi][1]);
        t.y = pk2bf(g[mi][2], g[mi][3]);
        *(uint2*)(DsT + (sl * 16 + l16) * 68 + mi * 16 + quad * 4) = t;
      }
    }

    // ---- QK^T for this wave's q-strip ----
    floatx4 s[4];
#pragma unroll
    for (int ni = 0; ni < 4; ++ni) s[ni] = fzero;
#pragma unroll
    for (int kk = 0; kk < 2; ++kk)
#pragma unroll
      for (int ni = 0; ni < 4; ++ni)
        s[ni] = __builtin_amdgcn_mfma_f32_16x16x32_bf16(aq[wave][kk], kf[ni][kk],
                                                        s[ni], 0, 0, 0);

    __syncthreads();  // A: CsT/DsT/offL ready

    float pv[4][4];
    if (lin) {
#pragma unroll
      for (int ni = 0; ni < 4; ++ni) {
        int kloc = ni * 16 + l16;
#pragma unroll
        for (int r = 0; r < 4; ++r) {
          int off68 = (qb4 + r - kloc + 63) * 68;
          pv[ni][r] = exp2f((s[ni][r] + bf2f(CsT[off68 + qb4 + r]) +
                             bf2f(DsT[off68 + kloc])) * sc2);
        }
      }
    } else {
#pragma unroll
      for (int ni = 0; ni < 4; ++ni) {
        int kloc = ni * 16 + l16;
#pragma unroll
        for (int r = 0; r < 4; ++r) {
          int off68 = offL[qb4 + r - kloc + 63];
          pv[ni][r] = exp2f((s[ni][r] + bf2f(CsT[off68 + qb4 + r]) +
                             bf2f(DsT[off68 + kloc])) * sc2);
        }
      }
    }
#pragma unroll
    for (int r = 0; r < 4; ++r) {
      float rs = pv[0][r] + pv[1][r] + pv[2][r] + pv[3][r];
      rs += __shfl_xor(rs, 1);
      rs += __shfl_xor(rs, 2);
      rs += __shfl_xor(rs, 4);
      rs += __shfl_xor(rs, 8);
      l_i[r] += rs;
    }
    // P: D-layout -> A-layout via per-wave strip
#pragma unroll
    for (int ni = 0; ni < 4; ++ni)
#pragma unroll
      for (int r = 0; r < 4; ++r)
        Pw[(quad * 4 + r) * 72 + ni * 16 + l16] = f2bf(pv[ni][r]);

    // PV: A from Ps, B (V^T) straight from global
#pragma unroll
    for (int kk = 0; kk < 2; ++kk) {
      short8 ap = *(const short8*)(Pw + l16 * 72 + kk * 32 + quad * 8);
#pragma unroll
      for (int ni = 0; ni < 4; ++ni) {
        short8 vv = *(const short8*)(Vg + (long)(ni * 16 + l16) * S_LEN + k0 +
                                     kk * 32 + quad * 8);
        acc[ni] = __builtin_amdgcn_mfma_f32_16x16x32_bf16(ap, vv, acc[ni], 0, 0, 0);
      }
    }
    __syncthreads();  // B: CsT/DsT/offL reads done before next overwrite
  }

#pragma unroll
  for (int ni = 0; ni < 4; ++ni) {
    int dd = ni * 16 + l16;
#pragma unroll
    for (int r = 0; r < 4; ++r) {
      int qrow = q0 + qb4 + r;
      ctx[((long)(b * S_LEN) + qrow) * DMODEL + h * HD + dd] = f2bf(acc[ni][r] / l_i[r]);
    }
  }
}

// ---------------- LayerNorm over rows of 1024 ----------------
__global__ __launch_bounds__(256) void ln_kernel(
    const float* __restrict__ x, const float* __restrict__ gamma,
    const float* __restrict__ beta, float* __restrict__ out) {
  const int row = blockIdx.x;
  const int tid = threadIdx.x;
  const float* xr = x + (long)row * DMODEL;
  float4 v = *(const float4*)(xr + (tid << 2));
  float s = v.x + v.y + v.z + v.w;
#pragma unroll
  for (int off = 32; off; off >>= 1) s += __shfl_xor(s, off);
  __shared__ float red[4];
  if ((tid & 63) == 0) red[tid >> 6] = s;
  __syncthreads();
  float mu = (red[0] + red[1] + red[2] + red[3]) * (1.0f / DMODEL);
  float dx0 = v.x - mu, dx1 = v.y - mu, dx2 = v.z - mu, dx3 = v.w - mu;
  float sq = dx0 * dx0 + dx1 * dx1 + dx2 * dx2 + dx3 * dx3;
#pragma unroll
  for (int off = 32; off; off >>= 1) sq += __shfl_xor(sq, off);
  __syncthreads();
  if ((tid & 63) == 0) red[tid >> 6] = sq;
  __syncthreads();
  float var = (red[0] + red[1] + red[2] + red[3]) * (1.0f / DMODEL);
  float rstd = 1.0f / sqrtf(var + 1e-7f);
  float4 g = *(const float4*)(gamma + (tid << 2));
  float4 be = *(const float4*)(beta + (tid << 2));
  float4 o = make_float4(dx0 * rstd * g.x + be.x, dx1 * rstd * g.y + be.y,
                         dx2 * rstd * g.z + be.z, dx3 * rstd * g.w + be.w);
  *(float4*)(out + (long)row * DMODEL + (tid << 2)) = o;
}

extern "C" void kernel_launch(void* const* d_in, const int* in_sizes, int n_in,
                              void* d_out, int out_size, void* d_ws, size_t ws_size,
                              hipStream_t stream) {
  (void)in_sizes; (void)n_in; (void)out_size; (void)ws_size;
  const float* hidden = (const float*)d_in[0];
  const float* rel = (const float*)d_in[2];
  const float* Wq = (const float*)d_in[3];
  const float* bq = (const float*)d_in[4];
  const float* Wk = (const float*)d_in[5];
  const float* bk = (const float*)d_in[6];
  const float* Wv = (const float*)d_in[7];
  const float* bv = (const float*)d_in[8];
  const float* Wo = (const float*)d_in[9];
  const float* bo = (const float*)d_in[10];
  const float* gamma = (const float*)d_in[11];
  const float* beta = (const float*)d_in[12];
  float* out = (float*)d_out;

  char* p = (char*)d_ws;
  auto carve = [&](size_t bytes) -> char* {
    char* r = p;
    p += (bytes + 255) & ~(size_t)255;
    return r;
  };
  u16* hid_bf = (u16*)carve((size_t)4096 * 1024 * 2);
  u16* rel_bf = (u16*)carve((size_t)512 * 1024 * 2);
  u16* wqkv_bf = (u16*)carve((size_t)3072 * 1024 * 2);
  u16* wo_bf = (u16*)carve((size_t)1024 * 1024 * 2);
  u16* qkv_rm = (u16*)carve((size_t)4096 * 3072 * 2);   // [B*S, 3072] bf16
  // pos_rm before Vtb: flash window B-reads may overrun by <=14 rows (never gathered)
  u16* pos_rm = (u16*)carve((size_t)512 * 2048 * 2);    // [512, 2048] bf16
  u16* Vtb = (u16*)carve((size_t)BATCH * NH * HD * S_LEN * 2);
  u16* ctx = (u16*)carve((size_t)4096 * 1024 * 2);
  float* tmp = (float*)carve((size_t)4096 * 1024 * 4);
  float* biascat = (float*)carve((size_t)3072 * 4);
  int* tab = (int*)carve((size_t)2047 * 4);

  const float inv_scale = 1.0f / sqrtf(192.0f);
  const float sc2 = inv_scale * 1.44269504089f;  // fold log2(e) for exp2f

  prep_kernel<<<dim3(16), dim3(256), 0, stream>>>(tab, bq, bk, bv, biascat);
  cast_all<<<dim3(8704), dim3(256), 0, stream>>>(hidden, rel, Wq, Wk, Wv, Wo, hid_bf,
                                                 rel_bf, wqkv_bf, wo_bf);

  // QKV: [4096,3072,1024] -> row-major bf16 (+bias)
  mgemm<<<dim3(24, 32), 256, 0, stream>>>(hid_bf, wqkv_bf, biascat, nullptr, qkv_rm,
                                          4096, 3072, 1024, 1);
  // pos projections: [512,2048,1024] over [Wq;Wk] -> row-major bf16 (+bias)
  mgemm<<<dim3(16, 4), 256, 0, stream>>>(rel_bf, wqkv_bf, biascat, nullptr, pos_rm,
                                         512, 2048, 1024, 1);
  // V -> [B,H,64,S]
  vtrans<<<dim3(16, NH, BATCH), 256, 0, stream>>>(qkv_rm, Vtb);

  // fused flash attention, direct-global fragments + on-chip bias recompute
  flash_mfma<<<dim3(16, NH, BATCH), 256, 0, stream>>>(qkv_rm, Vtb, pos_rm, tab, ctx, sc2);

  // out-proj + bias + residual (f32), then LN
  mgemm<<<dim3(8, 32), 256, 0, stream>>>(ctx, wo_bf, bo, hidden, tmp, 4096, 1024, 1024, 0);
  ln_kernel<<<dim3(4096), 256, 0, stream>>>(tmp, gamma, beta, out);
}

// Round 7
// 444.540 us; speedup vs baseline: 1.0360x; 1.0360x over previous
//
#include <hip/hip_runtime.h>
#include <math.h>

#define S_LEN 1024
#define DMODEL 1024
#define NH 16
#define HD 64
#define P2 512
#define BATCH 4

typedef unsigned short u16;
typedef __attribute__((ext_vector_type(8))) short short8;
typedef __attribute__((ext_vector_type(4))) float floatx4;

__device__ __forceinline__ u16 f2bf(float f) {
  unsigned u = __float_as_uint(f);
  unsigned r = u + 0x7FFFu + ((u >> 16) & 1u);
  return (u16)(r >> 16);
}
__device__ __forceinline__ float bf2f(u16 v) {
  return __uint_as_float(((unsigned)v) << 16);
}
__device__ __forceinline__ unsigned pk2bf(float a, float b) {
#if __has_builtin(__builtin_amdgcn_cvt_pk_bf16_f32)
  typedef __attribute__((ext_vector_type(2))) __bf16 bf2v;
  bf2v t = __builtin_amdgcn_cvt_pk_bf16_f32(a, b);
  return *(unsigned*)&t;
#else
  return (unsigned)f2bf(a) | ((unsigned)f2bf(b) << 16);
#endif
}
// async global->LDS, 16B per lane; lds dest = wave-uniform base + lane*16
__device__ __forceinline__ void gl_lds16(const void* g, void* l) {
  __builtin_amdgcn_global_load_lds(
      (const __attribute__((address_space(1))) void*)g,
      (__attribute__((address_space(3))) void*)l, 16, 0, 0);
}

// ---------------- prep: tab + concatenated bias ----------------
__global__ void prep_kernel(int* __restrict__ tab, const float* __restrict__ bq,
                            const float* __restrict__ bk, const float* __restrict__ bv,
                            float* __restrict__ biascat) {
  int t = blockIdx.x * blockDim.x + threadIdx.x;
  if (t < 2 * S_LEN - 1) {
    int rel = t - (S_LEN - 1);
    const int mid = 128;
    float abspos = (rel < mid && rel > -mid) ? (float)(mid - 1) : fabsf((float)rel);
    float bucket;
    if (abspos <= (float)mid) {
      bucket = (float)rel;
    } else {
      float den = (float)log(3.9921875);
      float lp = ceilf(logf(abspos / 128.0f) / den * 127.0f) + 128.0f;
      bucket = (rel > 0) ? lp : -lp;
    }
    int idx = (int)bucket + 256;
    idx = idx < 0 ? 0 : (idx > P2 - 1 ? P2 - 1 : idx);
    tab[t] = idx;
  }
  if (t < 3072) biascat[t] = t < 1024 ? bq[t] : (t < 2048 ? bk[t - 1024] : bv[t - 2048]);
}

// ---------------- single fused f32->bf16 cast over all inputs ----------------
__global__ __launch_bounds__(256) void cast_all(
    const float* __restrict__ h, const float* __restrict__ r,
    const float* __restrict__ wq, const float* __restrict__ wk,
    const float* __restrict__ wv, const float* __restrict__ wo,
    u16* __restrict__ hb, u16* __restrict__ rb,
    u16* __restrict__ wqkvb, u16* __restrict__ wob) {
  int b = blockIdx.x;
  const float* src;
  u16* dst;
  int off;
  if (b < 4096) { src = h; dst = hb; off = b; }
  else if (b < 4608) { src = r; dst = rb; off = b - 4096; }
  else if (b < 5632) { src = wq; dst = wqkvb; off = b - 4608; }
  else if (b < 6656) { src = wk; dst = wqkvb + 1024 * 1024; off = b - 5632; }
  else if (b < 7680) { src = wv; dst = wqkvb + 2 * 1024 * 1024; off = b - 6656; }
  else { src = wo; dst = wob; off = b - 7680; }
  long i = (long)off * 1024 + (threadIdx.x << 2);
  float4 v = *(const float4*)(src + i);
  uint2 o;
  o.x = pk2bf(v.x, v.y);
  o.y = pk2bf(v.z, v.w);
  *(uint2*)(dst + i) = o;
}

// ---------------- bf16 MFMA NT GEMM, 128x128 tile, BK=32 ----------------
// mode 0: f32 out + bias + resid (out-proj).  mode 1: bf16 row-major out + bias.
__global__ __launch_bounds__(256) void mgemm(
    const u16* __restrict__ A, const u16* __restrict__ Bw,
    const float* __restrict__ b0, const float* __restrict__ resid,
    void* out0, int M, int N, int K, int mode) {
  __shared__ u16 Al[128 * 32];
  __shared__ u16 Bl[128 * 32];
  const int tid = threadIdx.x;
  const int wave = tid >> 6, lane = tid & 63;
  const int quad = lane >> 4, l16 = lane & 15;
  const int m0 = blockIdx.y * 128, n0 = blockIdx.x * 128;

  const floatx4 fzero = {0.f, 0.f, 0.f, 0.f};
  floatx4 acc[4][4];
#pragma unroll
  for (int mi = 0; mi < 4; ++mi)
#pragma unroll
    for (int ni = 0; ni < 4; ++ni) acc[mi][ni] = fzero;

  const int wm = (wave & 1) * 64, wn = (wave >> 1) * 64;

  for (int k0 = 0; k0 < K; k0 += 32) {
#pragma unroll
    for (int i = 0; i < 2; ++i) {
      int ch = i * 256 + wave * 64 + lane;
      int row = ch >> 2, c = ch & 3;
      gl_lds16(A + (long)(m0 + row) * K + k0 + c * 8, Al + (i * 256 + wave * 64) * 8);
      gl_lds16(Bw + (long)(n0 + row) * K + k0 + c * 8, Bl + (i * 256 + wave * 64) * 8);
    }
    __syncthreads();
    short8 af[4], bf[4];
#pragma unroll
    for (int t = 0; t < 4; ++t) {
      af[t] = *(const short8*)(Al + (wm + t * 16 + l16) * 32 + quad * 8);
      bf[t] = *(const short8*)(Bl + (wn + t * 16 + l16) * 32 + quad * 8);
    }
#pragma unroll
    for (int mi = 0; mi < 4; ++mi)
#pragma unroll
      for (int ni = 0; ni < 4; ++ni)
        acc[mi][ni] =
            __builtin_amdgcn_mfma_f32_16x16x32_bf16(af[mi], bf[ni], acc[mi][ni], 0, 0, 0);
    __syncthreads();
  }

  if (mode == 0) {
    float* o = (float*)out0;
#pragma unroll
    for (int mi = 0; mi < 4; ++mi)
#pragma unroll
      for (int ni = 0; ni < 4; ++ni) {
        int n = n0 + wn + ni * 16 + l16;
#pragma unroll
        for (int r = 0; r < 4; ++r) {
          int m = m0 + wm + mi * 16 + quad * 4 + r;
          o[(long)m * N + n] = acc[mi][ni][r] + b0[n] + resid[(long)m * N + n];
        }
      }
  } else {
    u16* o = (u16*)out0;
#pragma unroll
    for (int mi = 0; mi < 4; ++mi)
#pragma unroll
      for (int ni = 0; ni < 4; ++ni) {
        int n = n0 + wn + ni * 16 + l16;
        float bias = b0[n];
        int mb = m0 + wm + mi * 16 + quad * 4;
#pragma unroll
        for (int r = 0; r < 4; ++r)
          o[(long)(mb + r) * N + n] = f2bf(acc[mi][ni][r] + bias);
      }
  }
}

// ---------------- V transpose: qkv_rm V-part -> Vt [B,H,64,S] ----------------
__global__ __launch_bounds__(256) void vtrans(const u16* __restrict__ qkv,
                                              u16* __restrict__ Vt) {
  __shared__ u16 tile[64][68];
  const int s0 = blockIdx.x * 64, h = blockIdx.y, b = blockIdx.z;
  const int t = threadIdx.x;
  const int r16 = t >> 4, c4 = (t & 15) << 2;
  const u16* src = qkv + ((long)(b * S_LEN + s0)) * 3072 + 2048 + h * HD;
#pragma unroll
  for (int i = 0; i < 4; ++i) {
    int row = i * 16 + r16;
    ushort4 v = *(const ushort4*)(src + (long)row * 3072 + c4);
    *(ushort4*)&tile[row][c4] = v;
  }
  __syncthreads();
  u16* dst = Vt + ((long)(b * NH + h) * HD) * S_LEN + s0;
#pragma unroll
  for (int i = 0; i < 4; ++i) {
    int dd = i * 16 + r16;
    ushort4 o;
    o.x = tile[c4 + 0][dd]; o.y = tile[c4 + 1][dd];
    o.z = tile[c4 + 2][dd]; o.w = tile[c4 + 3][dd];
    *(ushort4*)(dst + (long)dd * S_LEN + c4) = o;
  }
}

// ---------------- MFMA flash attention, v4 ----------------
// K/V LDS-staged (DMA); Q A-frags loaded once from global at start (no Qs).
// Bias windows recomputed on MFMA: Gq -> Cs row-major [qloc][132] (wave-private
// 16-row strips double as the P transpose buffer), Gk -> DsT [col][kloc].
// ak fragments serve both Gk A-operands and QK^T B-operands (identical layout).
__global__ __launch_bounds__(256, 3) void flash_mfma(
    const u16* __restrict__ qkv, const u16* __restrict__ Vt,
    const u16* __restrict__ pos, const int* __restrict__ tab,
    u16* __restrict__ ctx, float sc2) {
  __shared__ u16 Ks[64 * 64];
  __shared__ u16 Vs[64 * 64];     // [dd][k]
  __shared__ u16 Cs[64 * 132];    // Gq row-major; wave strips alias P buffer
  __shared__ u16 DsT[128 * 68];   // Gk^T [col][kloc]
  __shared__ u16 offL[128];       // tab[d]-base, e = d-d_min in [0,126]

  const int tid = threadIdx.x;
  const int wave = tid >> 6, lane = tid & 63;
  const int quad = lane >> 4, l16 = lane & 15;
  const int h = blockIdx.y, q0 = blockIdx.x * 64;
  const int b = blockIdx.z;

  const u16* Qg = qkv + ((long)(b * S_LEN + q0)) * 3072 + h * HD;
  const u16* Kg = qkv + ((long)(b * S_LEN)) * 3072 + 1024 + h * HD;
  const u16* Vg = Vt + ((long)(b * NH + h) * HD) * S_LEN;
  const u16* posq_g = pos + h * HD;         // [512,2048] rows, Wq cols
  const u16* posk_g = pos + 1024 + h * HD;  // Wk cols

  // Q A-fragments straight from global — one-time cost, amortized over 16 tiles
  short8 aq[4][2];
#pragma unroll
  for (int mi = 0; mi < 4; ++mi)
#pragma unroll
    for (int kk = 0; kk < 2; ++kk)
      aq[mi][kk] =
          *(const short8*)(Qg + (long)(mi * 16 + l16) * 3072 + kk * 32 + quad * 8);

  const floatx4 fzero = {0.f, 0.f, 0.f, 0.f};
  floatx4 acc[4];
#pragma unroll
  for (int ni = 0; ni < 4; ++ni) acc[ni] = fzero;
  float l_i[4] = {0.f, 0.f, 0.f, 0.f};

  u16* Pw = Cs + wave * 16 * 132;  // own-wave strip: gather reads precede P writes
  const int qb4 = wave * 16 + quad * 4;

  for (int k0 = 0; k0 < S_LEN; k0 += 64) {
    const int dmin = q0 - k0 - 63;
    const int base = tab[dmin + 1023];
    const int w = tab[dmin + 1023 + 126] - base + 1;  // monotone => 1..127
    const int nsl = (w + 15) >> 4;
    const bool lin = (dmin >= -127) && (dmin <= 1);   // tile d-range fully linear
    if (!lin && tid < 127) offL[tid] = (u16)(tab[dmin + 1023 + tid] - base);

#pragma unroll
    for (int i = 0; i < 2; ++i) {
      int ch = i * 256 + wave * 64 + lane;
      int row = ch >> 3, c = ch & 7;
      gl_lds16(Kg + (long)(k0 + row) * 3072 + c * 8, Ks + (i * 256 + wave * 64) * 8);
      gl_lds16(Vg + (long)row * S_LEN + k0 + c * 8, Vs + (i * 256 + wave * 64) * 8);
    }
    __syncthreads();  // #1: K,V staged; offL visible

    // K fragments from LDS once: serve Gk-A and QK-B
    short8 ak[4][2];
#pragma unroll
    for (int ni = 0; ni < 4; ++ni)
#pragma unroll
      for (int kk = 0; kk < 2; ++kk)
        ak[ni][kk] = *(const short8*)(Ks + (ni * 16 + l16) * 64 + kk * 32 + quad * 8);

    // ---- Gq slices (wave-strided) -> Cs row-major ----
    for (int sl = wave; sl < nsl; sl += 4) {
      floatx4 g[4];
#pragma unroll
      for (int mi = 0; mi < 4; ++mi) g[mi] = fzero;
      int wrow = base + sl * 16 + l16;
#pragma unroll
      for (int kk = 0; kk < 2; ++kk) {
        short8 bp = *(const short8*)(posk_g + (long)wrow * 2048 + kk * 32 + quad * 8);
#pragma unroll
        for (int mi = 0; mi < 4; ++mi)
          g[mi] = __builtin_amdgcn_mfma_f32_16x16x32_bf16(aq[mi][kk], bp, g[mi], 0, 0, 0);
      }
#pragma unroll
      for (int mi = 0; mi < 4; ++mi)
#pragma unroll
        for (int r = 0; r < 4; ++r)
          Cs[(mi * 16 + quad * 4 + r) * 132 + sl * 16 + l16] = f2bf(g[mi][r]);
    }
    // ---- Gk slices -> DsT (packed writes) ----
    for (int sl = wave; sl < nsl; sl += 4) {
      floatx4 g[4];
#pragma unroll
      for (int mi = 0; mi < 4; ++mi) g[mi] = fzero;
      int wrow = base + sl * 16 + l16;
#pragma unroll
      for (int kk = 0; kk < 2; ++kk) {
        short8 bp = *(const short8*)(posq_g + (long)wrow * 2048 + kk * 32 + quad * 8);
#pragma unroll
        for (int mi = 0; mi < 4; ++mi)
          g[mi] = __builtin_amdgcn_mfma_f32_16x16x32_bf16(ak[mi][kk], bp, g[mi], 0, 0, 0);
      }
#pragma unroll
      for (int mi = 0; mi < 4; ++mi) {
        uint2 t;
        t.x = pk2bf(g[mi][0], g[mi][1]);
        t.y = pk2bf(g[mi][2], g[mi][3]);
        *(uint2*)(DsT + (sl * 16 + l16) * 68 + mi * 16 + quad * 4) = t;
      }
    }

    // ---- QK^T for this wave's q-strip (B-operands = ak, no extra LDS reads) ----
    floatx4 s[4];
#pragma unroll
    for (int ni = 0; ni < 4; ++ni) s[ni] = fzero;
#pragma unroll
    for (int kk = 0; kk < 2; ++kk)
#pragma unroll
      for (int ni = 0; ni < 4; ++ni)
        s[ni] = __builtin_amdgcn_mfma_f32_16x16x32_bf16(aq[wave][kk], ak[ni][kk],
                                                        s[ni], 0, 0, 0);

    __syncthreads();  // #2: Cs/DsT complete

    float pv[4][4];
    if (lin) {
#pragma unroll
      for (int ni = 0; ni < 4; ++ni) {
        int kloc = ni * 16 + l16;
#pragma unroll
        for (int r = 0; r < 4; ++r) {
          int off = qb4 + r - kloc + 63;
          pv[ni][r] = exp2f((s[ni][r] + bf2f(Cs[(qb4 + r) * 132 + off]) +
                             bf2f(DsT[off * 68 + kloc])) * sc2);
        }
      }
    } else {
#pragma unroll
      for (int ni = 0; ni < 4; ++ni) {
        int kloc = ni * 16 + l16;
#pragma unroll
        for (int r = 0; r < 4; ++r) {
          int off = offL[qb4 + r - kloc + 63];
          pv[ni][r] = exp2f((s[ni][r] + bf2f(Cs[(qb4 + r) * 132 + off]) +
                             bf2f(DsT[off * 68 + kloc])) * sc2);
        }
      }
    }
#pragma unroll
    for (int r = 0; r < 4; ++r) {
      float rs = pv[0][r] + pv[1][r] + pv[2][r] + pv[3][r];
      rs += __shfl_xor(rs, 1);
      rs += __shfl_xor(rs, 2);
      rs += __shfl_xor(rs, 4);
      rs += __shfl_xor(rs, 8);
      l_i[r] += rs;
    }
    // P: D-layout -> A-layout via own-wave Cs strip (reads of strip done above)
#pragma unroll
    for (int ni = 0; ni < 4; ++ni)
#pragma unroll
      for (int r = 0; r < 4; ++r)
        Pw[(quad * 4 + r) * 72 + ni * 16 + l16] = f2bf(pv[ni][r]);

#pragma unroll
    for (int kk = 0; kk < 2; ++kk) {
      short8 ap = *(const short8*)(Pw + l16 * 72 + kk * 32 + quad * 8);
#pragma unroll
      for (int ni = 0; ni < 4; ++ni) {
        short8 vv = *(const short8*)(Vs + (ni * 16 + l16) * 64 + kk * 32 + quad * 8);
        acc[ni] = __builtin_amdgcn_mfma_f32_16x16x32_bf16(ap, vv, acc[ni], 0, 0, 0);
      }
    }
    __syncthreads();  // #3: all reads done before next tile's DMA/slice writes
  }

#pragma unroll
  for (int ni = 0; ni < 4; ++ni) {
    int dd = ni * 16 + l16;
#pragma unroll
    for (int r = 0; r < 4; ++r) {
      int qrow = q0 + qb4 + r;
      ctx[((long)(b * S_LEN) + qrow) * DMODEL + h * HD + dd] = f2bf(acc[ni][r] / l_i[r]);
    }
  }
}

// ---------------- LayerNorm over rows of 1024 ----------------
__global__ __launch_bounds__(256) void ln_kernel(
    const float* __restrict__ x, const float* __restrict__ gamma,
    const float* __restrict__ beta, float* __restrict__ out) {
  const int row = blockIdx.x;
  const int tid = threadIdx.x;
  const float* xr = x + (long)row * DMODEL;
  float4 v = *(const float4*)(xr + (tid << 2));
  float s = v.x + v.y + v.z + v.w;
#pragma unroll
  for (int off = 32; off; off >>= 1) s += __shfl_xor(s, off);
  __shared__ float red[4];
  if ((tid & 63) == 0) red[tid >> 6] = s;
  __syncthreads();
  float mu = (red[0] + red[1] + red[2] + red[3]) * (1.0f / DMODEL);
  float dx0 = v.x - mu, dx1 = v.y - mu, dx2 = v.z - mu, dx3 = v.w - mu;
  float sq = dx0 * dx0 + dx1 * dx1 + dx2 * dx2 + dx3 * dx3;
#pragma unroll
  for (int off = 32; off; off >>= 1) sq += __shfl_xor(sq, off);
  __syncthreads();
  if ((tid & 63) == 0) red[tid >> 6] = sq;
  __syncthreads();
  float var = (red[0] + red[1] + red[2] + red[3]) * (1.0f / DMODEL);
  float rstd = 1.0f / sqrtf(var + 1e-7f);
  float4 g = *(const float4*)(gamma + (tid << 2));
  float4 be = *(const float4*)(beta + (tid << 2));
  float4 o = make_float4(dx0 * rstd * g.x + be.x, dx1 * rstd * g.y + be.y,
                         dx2 * rstd * g.z + be.z, dx3 * rstd * g.w + be.w);
  *(float4*)(out + (long)row * DMODEL + (tid << 2)) = o;
}

extern "C" void kernel_launch(void* const* d_in, const int* in_sizes, int n_in,
                              void* d_out, int out_size, void* d_ws, size_t ws_size,
                              hipStream_t stream) {
  (void)in_sizes; (void)n_in; (void)out_size; (void)ws_size;
  const float* hidden = (const float*)d_in[0];
  const float* rel = (const float*)d_in[2];
  const float* Wq = (const float*)d_in[3];
  const float* bq = (const float*)d_in[4];
  const float* Wk = (const float*)d_in[5];
  const float* bk = (const float*)d_in[6];
  const float* Wv = (const float*)d_in[7];
  const float* bv = (const float*)d_in[8];
  const float* Wo = (const float*)d_in[9];
  const float* bo = (const float*)d_in[10];
  const float* gamma = (const float*)d_in[11];
  const float* beta = (const float*)d_in[12];
  float* out = (float*)d_out;

  char* p = (char*)d_ws;
  auto carve = [&](size_t bytes) -> char* {
    char* r = p;
    p += (bytes + 255) & ~(size_t)255;
    return r;
  };
  u16* hid_bf = (u16*)carve((size_t)4096 * 1024 * 2);
  u16* rel_bf = (u16*)carve((size_t)512 * 1024 * 2);
  u16* wqkv_bf = (u16*)carve((size_t)3072 * 1024 * 2);
  u16* wo_bf = (u16*)carve((size_t)1024 * 1024 * 2);
  u16* qkv_rm = (u16*)carve((size_t)4096 * 3072 * 2);   // [B*S, 3072] bf16
  // pos_rm before Vtb: flash window B-reads may overrun by <=14 rows (never gathered)
  u16* pos_rm = (u16*)carve((size_t)512 * 2048 * 2);    // [512, 2048] bf16
  u16* Vtb = (u16*)carve((size_t)BATCH * NH * HD * S_LEN * 2);
  u16* ctx = (u16*)carve((size_t)4096 * 1024 * 2);
  float* tmp = (float*)carve((size_t)4096 * 1024 * 4);
  float* biascat = (float*)carve((size_t)3072 * 4);
  int* tab = (int*)carve((size_t)2047 * 4);

  const float inv_scale = 1.0f / sqrtf(192.0f);
  const float sc2 = inv_scale * 1.44269504089f;  // fold log2(e) for exp2f

  prep_kernel<<<dim3(16), dim3(256), 0, stream>>>(tab, bq, bk, bv, biascat);
  cast_all<<<dim3(8704), dim3(256), 0, stream>>>(hidden, rel, Wq, Wk, Wv, Wo, hid_bf,
                                                 rel_bf, wqkv_bf, wo_bf);

  // QKV: [4096,3072,1024] -> row-major bf16 (+bias)
  mgemm<<<dim3(24, 32), 256, 0, stream>>>(hid_bf, wqkv_bf, biascat, nullptr, qkv_rm,
                                          4096, 3072, 1024, 1);
  // pos projections: [512,2048,1024] over [Wq;Wk] -> row-major bf16 (+bias)
  mgemm<<<dim3(16, 4), 256, 0, stream>>>(rel_bf, wqkv_bf, biascat, nullptr, pos_rm,
                                         512, 2048, 1024, 1);
  // V -> [B,H,64,S]
  vtrans<<<dim3(16, NH, BATCH), 256, 0, stream>>>(qkv_rm, Vtb);

  // fused flash attention, LDS-staged K/V + on-chip bias recompute
  flash_mfma<<<dim3(16, NH, BATCH), 256, 0, stream>>>(qkv_rm, Vtb, pos_rm, tab, ctx, sc2);

  // out-proj + bias + residual (f32), then LN
  mgemm<<<dim3(8, 32), 256, 0, stream>>>(ctx, wo_bf, bo, hidden, tmp, 4096, 1024, 1024, 0);
  ln_kernel<<<dim3(4096), 256, 0, stream>>>(tmp, gamma, beta, out);
}

// Round 8
// 402.910 us; speedup vs baseline: 1.1431x; 1.1033x over previous
//
#include <hip/hip_runtime.h>
#include <math.h>

#define S_LEN 1024
#define DMODEL 1024
#define NH 16
#define HD 64
#define P2 512
#define BATCH 4

typedef unsigned short u16;
typedef __attribute__((ext_vector_type(8))) short short8;
typedef __attribute__((ext_vector_type(4))) float floatx4;

__device__ __forceinline__ u16 f2bf(float f) {
  unsigned u = __float_as_uint(f);
  unsigned r = u + 0x7FFFu + ((u >> 16) & 1u);
  return (u16)(r >> 16);
}
__device__ __forceinline__ float bf2f(u16 v) {
  return __uint_as_float(((unsigned)v) << 16);
}
__device__ __forceinline__ unsigned pk2bf(float a, float b) {
#if __has_builtin(__builtin_amdgcn_cvt_pk_bf16_f32)
  typedef __attribute__((ext_vector_type(2))) __bf16 bf2v;
  bf2v t = __builtin_amdgcn_cvt_pk_bf16_f32(a, b);
  return *(unsigned*)&t;
#else
  return (unsigned)f2bf(a) | ((unsigned)f2bf(b) << 16);
#endif
}
// async global->LDS, 16B per lane; lds dest = wave-uniform base + lane*16
__device__ __forceinline__ void gl_lds16(const void* g, void* l) {
  __builtin_amdgcn_global_load_lds(
      (const __attribute__((address_space(1))) void*)g,
      (__attribute__((address_space(3))) void*)l, 16, 0, 0);
}

// ---------------- prep: tab + concatenated bias ----------------
__global__ void prep_kernel(int* __restrict__ tab, const float* __restrict__ bq,
                            const float* __restrict__ bk, const float* __restrict__ bv,
                            float* __restrict__ biascat) {
  int t = blockIdx.x * blockDim.x + threadIdx.x;
  if (t < 2 * S_LEN - 1) {
    int rel = t - (S_LEN - 1);
    const int mid = 128;
    float abspos = (rel < mid && rel > -mid) ? (float)(mid - 1) : fabsf((float)rel);
    float bucket;
    if (abspos <= (float)mid) {
      bucket = (float)rel;
    } else {
      float den = (float)log(3.9921875);
      float lp = ceilf(logf(abspos / 128.0f) / den * 127.0f) + 128.0f;
      bucket = (rel > 0) ? lp : -lp;
    }
    int idx = (int)bucket + 256;
    idx = idx < 0 ? 0 : (idx > P2 - 1 ? P2 - 1 : idx);
    tab[t] = idx;
  }
  if (t < 3072) biascat[t] = t < 1024 ? bq[t] : (t < 2048 ? bk[t - 1024] : bv[t - 2048]);
}

// ---------------- single fused f32->bf16 cast over all inputs ----------------
__global__ __launch_bounds__(256) void cast_all(
    const float* __restrict__ h, const float* __restrict__ r,
    const float* __restrict__ wq, const float* __restrict__ wk,
    const float* __restrict__ wv, const float* __restrict__ wo,
    u16* __restrict__ hb, u16* __restrict__ rb,
    u16* __restrict__ wqkvb, u16* __restrict__ wob) {
  int b = blockIdx.x;
  const float* src;
  u16* dst;
  int off;
  if (b < 4096) { src = h; dst = hb; off = b; }
  else if (b < 4608) { src = r; dst = rb; off = b - 4096; }
  else if (b < 5632) { src = wq; dst = wqkvb; off = b - 4608; }
  else if (b < 6656) { src = wk; dst = wqkvb + 1024 * 1024; off = b - 5632; }
  else if (b < 7680) { src = wv; dst = wqkvb + 2 * 1024 * 1024; off = b - 6656; }
  else { src = wo; dst = wob; off = b - 7680; }
  long i = (long)off * 1024 + (threadIdx.x << 2);
  float4 v = *(const float4*)(src + i);
  uint2 o;
  o.x = pk2bf(v.x, v.y);
  o.y = pk2bf(v.z, v.w);
  *(uint2*)(dst + i) = o;
}

// ---------------- bf16 MFMA NT GEMM, 128x128 tile, BK=32 ----------------
// mode 0: f32 out + bias + resid (out-proj).
// mode 1: bf16 row-major out + bias, LDS-transposed coalesced epilogue.
__global__ __launch_bounds__(256) void mgemm(
    const u16* __restrict__ A, const u16* __restrict__ Bw,
    const float* __restrict__ b0, const float* __restrict__ resid,
    void* out0, int M, int N, int K, int mode) {
  __shared__ u16 Stage[2][128 * 32];
  u16* Al = Stage[0];
  u16* Bl = Stage[1];
  const int tid = threadIdx.x;
  const int wave = tid >> 6, lane = tid & 63;
  const int quad = lane >> 4, l16 = lane & 15;
  const int m0 = blockIdx.y * 128, n0 = blockIdx.x * 128;

  const floatx4 fzero = {0.f, 0.f, 0.f, 0.f};
  floatx4 acc[4][4];
#pragma unroll
  for (int mi = 0; mi < 4; ++mi)
#pragma unroll
    for (int ni = 0; ni < 4; ++ni) acc[mi][ni] = fzero;

  const int wm = (wave & 1) * 64, wn = (wave >> 1) * 64;

  for (int k0 = 0; k0 < K; k0 += 32) {
#pragma unroll
    for (int i = 0; i < 2; ++i) {
      int ch = i * 256 + wave * 64 + lane;
      int row = ch >> 2, c = ch & 3;
      gl_lds16(A + (long)(m0 + row) * K + k0 + c * 8, Al + (i * 256 + wave * 64) * 8);
      gl_lds16(Bw + (long)(n0 + row) * K + k0 + c * 8, Bl + (i * 256 + wave * 64) * 8);
    }
    __syncthreads();
    short8 af[4], bf[4];
#pragma unroll
    for (int t = 0; t < 4; ++t) {
      af[t] = *(const short8*)(Al + (wm + t * 16 + l16) * 32 + quad * 8);
      bf[t] = *(const short8*)(Bl + (wn + t * 16 + l16) * 32 + quad * 8);
    }
#pragma unroll
    for (int mi = 0; mi < 4; ++mi)
#pragma unroll
      for (int ni = 0; ni < 4; ++ni)
        acc[mi][ni] =
            __builtin_amdgcn_mfma_f32_16x16x32_bf16(af[mi], bf[ni], acc[mi][ni], 0, 0, 0);
    __syncthreads();
  }

  if (mode == 0) {
    float* o = (float*)out0;
#pragma unroll
    for (int mi = 0; mi < 4; ++mi)
#pragma unroll
      for (int ni = 0; ni < 4; ++ni) {
        int n = n0 + wn + ni * 16 + l16;
#pragma unroll
        for (int r = 0; r < 4; ++r) {
          int m = m0 + wm + mi * 16 + quad * 4 + r;
          o[(long)m * N + n] = acc[mi][ni][r] + b0[n] + resid[(long)m * N + n];
        }
      }
  } else {
    u16* o = (u16*)out0;
    u16* T = &Stage[0][0];  // 32 x 132 u16 = 8448 B, fits in Stage (16 KB)
    const int wp = wave & 1;
    float biasv[4];
#pragma unroll
    for (int ni = 0; ni < 4; ++ni) biasv[ni] = b0[n0 + wn + ni * 16 + l16];
#pragma unroll
    for (int p = 0; p < 4; ++p) {
      // waves with wm=0 fill T rows 0..15 (rows m0+p*16+..), wm=64 fill rows 16..31
#pragma unroll
      for (int ni = 0; ni < 4; ++ni) {
        int cl = wn + ni * 16 + l16;
#pragma unroll
        for (int r = 0; r < 4; ++r)
          T[(wp * 16 + quad * 4 + r) * 132 + cl] = f2bf(acc[p][ni][r] + biasv[ni]);
      }
      __syncthreads();
#pragma unroll
      for (int u = 0; u < 4; ++u) {
        int ch = u * 256 + tid;
        int row = ch >> 5, c4 = (ch & 31) << 2;
        int gr = m0 + (row >> 4) * 64 + p * 16 + (row & 15);
        *(ushort4*)(o + (long)gr * N + n0 + c4) = *(const ushort4*)(T + row * 132 + c4);
      }
      if (p < 3) __syncthreads();
    }
  }
}

// ---------------- V transpose: qkv_rm V-part -> Vt [B,H,64,S] ----------------
__global__ __launch_bounds__(256) void vtrans(const u16* __restrict__ qkv,
                                              u16* __restrict__ Vt) {
  __shared__ u16 tile[64][68];
  const int s0 = blockIdx.x * 64, h = blockIdx.y, b = blockIdx.z;
  const int t = threadIdx.x;
  const int r16 = t >> 4, c4 = (t & 15) << 2;
  const u16* src = qkv + ((long)(b * S_LEN + s0)) * 3072 + 2048 + h * HD;
#pragma unroll
  for (int i = 0; i < 4; ++i) {
    int row = i * 16 + r16;
    ushort4 v = *(const ushort4*)(src + (long)row * 3072 + c4);
    *(ushort4*)&tile[row][c4] = v;
  }
  __syncthreads();
  u16* dst = Vt + ((long)(b * NH + h) * HD) * S_LEN + s0;
#pragma unroll
  for (int i = 0; i < 4; ++i) {
    int dd = i * 16 + r16;
    ushort4 o;
    o.x = tile[c4 + 0][dd]; o.y = tile[c4 + 1][dd];
    o.z = tile[c4 + 2][dd]; o.w = tile[c4 + 3][dd];
    *(ushort4*)(dst + (long)dd * S_LEN + c4) = o;
  }
}

// ---------------- MFMA flash attention, v5 (r5 structure + occupancy 3/CU) ------
// LDS 52.5 KB: K/V share one buffer (K dead after ak regs; extra barrier, V-DMA
// hidden under MFMA phase); P strips alias the Q staging buffer (Q read pre-loop).
// Bias windows recomputed on MFMA into CsT/DsT [col][row] (stride 68); offL holds
// (tab[d]-base)*68 shared by both gathers; diagonal tiles use arithmetic offsets.
__global__ __launch_bounds__(256) void flash_mfma(
    const u16* __restrict__ qkv, const u16* __restrict__ Vt,
    const u16* __restrict__ pos, const int* __restrict__ tab,
    u16* __restrict__ ctx, float sc2) {
  __shared__ u16 KVs[64 * 64];      // 8 KB: K, then V (same tile)
  __shared__ u16 QPs[4 * 16 * 72];  // 9 KB: Q staging pre-loop, P strips in-loop
  __shared__ u16 CsT[128 * 68];     // Gq^T [off][qloc]
  __shared__ u16 DsT[128 * 68];     // Gk^T [off][kloc]
  __shared__ u16 offL[128];         // (tab[d]-base)*68

  const int tid = threadIdx.x;
  const int wave = tid >> 6, lane = tid & 63;
  const int quad = lane >> 4, l16 = lane & 15;
  const int h = blockIdx.y, q0 = blockIdx.x * 64;
  const int b = blockIdx.z;

  const u16* Qg = qkv + ((long)(b * S_LEN + q0)) * 3072 + h * HD;
  const u16* Kg = qkv + ((long)(b * S_LEN)) * 3072 + 1024 + h * HD;
  const u16* Vg = Vt + ((long)(b * NH + h) * HD) * S_LEN;
  const u16* posq_g = pos + h * HD;         // [512,2048] rows, Wq cols
  const u16* posk_g = pos + 1024 + h * HD;  // Wk cols

  // stage Q through LDS (region later reused as P strips)
#pragma unroll
  for (int i = 0; i < 2; ++i) {
    int ch = i * 256 + wave * 64 + lane;
    int row = ch >> 3, c = ch & 7;
    gl_lds16(Qg + (long)row * 3072 + c * 8, QPs + (i * 256 + wave * 64) * 8);
  }
  __syncthreads();
  short8 aq[4][2];
#pragma unroll
  for (int mi = 0; mi < 4; ++mi)
#pragma unroll
    for (int kk = 0; kk < 2; ++kk)
      aq[mi][kk] = *(const short8*)(QPs + (mi * 16 + l16) * 64 + kk * 32 + quad * 8);

  const floatx4 fzero = {0.f, 0.f, 0.f, 0.f};
  floatx4 acc[4];
#pragma unroll
  for (int ni = 0; ni < 4; ++ni) acc[ni] = fzero;
  float l_i[4] = {0.f, 0.f, 0.f, 0.f};

  u16* Pw = QPs + wave * 16 * 72;
  const int qb4 = wave * 16 + quad * 4;

  for (int k0 = 0; k0 < S_LEN; k0 += 64) {
    const int dmin = q0 - k0 - 63;
    const int base = tab[dmin + 1023];
    const int w = tab[dmin + 1023 + 126] - base + 1;  // monotone => 1..127
    const int nsl = (w + 15) >> 4;
    const bool lin = (dmin >= -127) && (dmin <= 1);   // tile d-range fully linear
    if (!lin && tid < 127) offL[tid] = (u16)((tab[dmin + 1023 + tid] - base) * 68);

    // K -> KVs
#pragma unroll
    for (int i = 0; i < 2; ++i) {
      int ch = i * 256 + wave * 64 + lane;
      int row = ch >> 3, c = ch & 7;
      gl_lds16(Kg + (long)(k0 + row) * 3072 + c * 8, KVs + (i * 256 + wave * 64) * 8);
    }
    __syncthreads();  // A: K staged; offL visible

    // K fragments once: serve Gk-A and QK-B
    short8 ak[4][2];
#pragma unroll
    for (int ni = 0; ni < 4; ++ni)
#pragma unroll
      for (int kk = 0; kk < 2; ++kk)
        ak[ni][kk] = *(const short8*)(KVs + (ni * 16 + l16) * 64 + kk * 32 + quad * 8);
    __syncthreads();  // B: all waves own ak; KVs free for V

    // V -> KVs (async; hidden under the MFMA phase below)
#pragma unroll
    for (int i = 0; i < 2; ++i) {
      int ch = i * 256 + wave * 64 + lane;
      int row = ch >> 3, c = ch & 7;
      gl_lds16(Vg + (long)row * S_LEN + k0 + c * 8, KVs + (i * 256 + wave * 64) * 8);
    }

    // ---- Gq slices (wave-strided) -> CsT ----
    for (int sl = wave; sl < nsl; sl += 4) {
      floatx4 g[4];
#pragma unroll
      for (int mi = 0; mi < 4; ++mi) g[mi] = fzero;
      int wrow = base + sl * 16 + l16;
#pragma unroll
      for (int kk = 0; kk < 2; ++kk) {
        short8 bp = *(const short8*)(posk_g + (long)wrow * 2048 + kk * 32 + quad * 8);
#pragma unroll
        for (int mi = 0; mi < 4; ++mi)
          g[mi] = __builtin_amdgcn_mfma_f32_16x16x32_bf16(aq[mi][kk], bp, g[mi], 0, 0, 0);
      }
#pragma unroll
      for (int mi = 0; mi < 4; ++mi) {
        uint2 t;
        t.x = pk2bf(g[mi][0], g[mi][1]);
        t.y = pk2bf(g[mi][2], g[mi][3]);
        *(uint2*)(CsT + (sl * 16 + l16) * 68 + mi * 16 + quad * 4) = t;
      }
    }
    // ---- Gk slices -> DsT ----
    for (int sl = wave; sl < nsl; sl += 4) {
      floatx4 g[4];
#pragma unroll
      for (int mi = 0; mi < 4; ++mi) g[mi] = fzero;
      int wrow = base + sl * 16 + l16;
#pragma unroll
      for (int kk = 0; kk < 2; ++kk) {
        short8 bp = *(const short8*)(posq_g + (long)wrow * 2048 + kk * 32 + quad * 8);
#pragma unroll
        for (int mi = 0; mi < 4; ++mi)
          g[mi] = __builtin_amdgcn_mfma_f32_16x16x32_bf16(ak[mi][kk], bp, g[mi], 0, 0, 0);
      }
#pragma unroll
      for (int mi = 0; mi < 4; ++mi) {
        uint2 t;
        t.x = pk2bf(g[mi][0], g[mi][1]);
        t.y = pk2bf(g[mi][2], g[mi][3]);
        *(uint2*)(DsT + (sl * 16 + l16) * 68 + mi * 16 + quad * 4) = t;
      }
    }

    // ---- QK^T for this wave's q-strip (B-operands = ak) ----
    floatx4 s[4];
#pragma unroll
    for (int ni = 0; ni < 4; ++ni) s[ni] = fzero;
#pragma unroll
    for (int kk = 0; kk < 2; ++kk)
#pragma unroll
      for (int ni = 0; ni < 4; ++ni)
        s[ni] = __builtin_amdgcn_mfma_f32_16x16x32_bf16(aq[wave][kk], ak[ni][kk],
                                                        s[ni], 0, 0, 0);

    __syncthreads();  // C: V staged; CsT/DsT complete

    float pv[4][4];
    if (lin) {
#pragma unroll
      for (int ni = 0; ni < 4; ++ni) {
        int kloc = ni * 16 + l16;
#pragma unroll
        for (int r = 0; r < 4; ++r) {
          int off68 = (qb4 + r - kloc + 63) * 68;
          pv[ni][r] = exp2f((s[ni][r] + bf2f(CsT[off68 + qb4 + r]) +
                             bf2f(DsT[off68 + kloc])) * sc2);
        }
      }
    } else {
#pragma unroll
      for (int ni = 0; ni < 4; ++ni) {
        int kloc = ni * 16 + l16;
#pragma unroll
        for (int r = 0; r < 4; ++r) {
          int off68 = offL[qb4 + r - kloc + 63];
          pv[ni][r] = exp2f((s[ni][r] + bf2f(CsT[off68 + qb4 + r]) +
                             bf2f(DsT[off68 + kloc])) * sc2);
        }
      }
    }
#pragma unroll
    for (int r = 0; r < 4; ++r) {
      float rs = pv[0][r] + pv[1][r] + pv[2][r] + pv[3][r];
      rs += __shfl_xor(rs, 1);
      rs += __shfl_xor(rs, 2);
      rs += __shfl_xor(rs, 4);
      rs += __shfl_xor(rs, 8);
      l_i[r] += rs;
    }
    // P: D-layout -> A-layout via per-wave strip in QPs
#pragma unroll
    for (int ni = 0; ni < 4; ++ni)
#pragma unroll
      for (int r = 0; r < 4; ++r)
        Pw[(quad * 4 + r) * 72 + ni * 16 + l16] = f2bf(pv[ni][r]);

#pragma unroll
    for (int kk = 0; kk < 2; ++kk) {
      short8 ap = *(const short8*)(Pw + l16 * 72 + kk * 32 + quad * 8);
#pragma unroll
      for (int ni = 0; ni < 4; ++ni) {
        short8 vv = *(const short8*)(KVs + (ni * 16 + l16) * 64 + kk * 32 + quad * 8);
        acc[ni] = __builtin_amdgcn_mfma_f32_16x16x32_bf16(ap, vv, acc[ni], 0, 0, 0);
      }
    }
    __syncthreads();  // D: all reads done before next tile overwrites
  }

#pragma unroll
  for (int ni = 0; ni < 4; ++ni) {
    int dd = ni * 16 + l16;
#pragma unroll
    for (int r = 0; r < 4; ++r) {
      int qrow = q0 + qb4 + r;
      ctx[((long)(b * S_LEN) + qrow) * DMODEL + h * HD + dd] = f2bf(acc[ni][r] / l_i[r]);
    }
  }
}

// ---------------- LayerNorm over rows of 1024 ----------------
__global__ __launch_bounds__(256) void ln_kernel(
    const float* __restrict__ x, const float* __restrict__ gamma,
    const float* __restrict__ beta, float* __restrict__ out) {
  const int row = blockIdx.x;
  const int tid = threadIdx.x;
  const float* xr = x + (long)row * DMODEL;
  float4 v = *(const float4*)(xr + (tid << 2));
  float s = v.x + v.y + v.z + v.w;
#pragma unroll
  for (int off = 32; off; off >>= 1) s += __shfl_xor(s, off);
  __shared__ float red[4];
  if ((tid & 63) == 0) red[tid >> 6] = s;
  __syncthreads();
  float mu = (red[0] + red[1] + red[2] + red[3]) * (1.0f / DMODEL);
  float dx0 = v.x - mu, dx1 = v.y - mu, dx2 = v.z - mu, dx3 = v.w - mu;
  float sq = dx0 * dx0 + dx1 * dx1 + dx2 * dx2 + dx3 * dx3;
#pragma unroll
  for (int off = 32; off; off >>= 1) sq += __shfl_xor(sq, off);
  __syncthreads();
  if ((tid & 63) == 0) red[tid >> 6] = sq;
  __syncthreads();
  float var = (red[0] + red[1] + red[2] + red[3]) * (1.0f / DMODEL);
  float rstd = 1.0f / sqrtf(var + 1e-7f);
  float4 g = *(const float4*)(gamma + (tid << 2));
  float4 be = *(const float4*)(beta + (tid << 2));
  float4 o = make_float4(dx0 * rstd * g.x + be.x, dx1 * rstd * g.y + be.y,
                         dx2 * rstd * g.z + be.z, dx3 * rstd * g.w + be.w);
  *(float4*)(out + (long)row * DMODEL + (tid << 2)) = o;
}

extern "C" void kernel_launch(void* const* d_in, const int* in_sizes, int n_in,
                              void* d_out, int out_size, void* d_ws, size_t ws_size,
                              hipStream_t stream) {
  (void)in_sizes; (void)n_in; (void)out_size; (void)ws_size;
  const float* hidden = (const float*)d_in[0];
  const float* rel = (const float*)d_in[2];
  const float* Wq = (const float*)d_in[3];
  const float* bq = (const float*)d_in[4];
  const float* Wk = (const float*)d_in[5];
  const float* bk = (const float*)d_in[6];
  const float* Wv = (const float*)d_in[7];
  const float* bv = (const float*)d_in[8];
  const float* Wo = (const float*)d_in[9];
  const float* bo = (const float*)d_in[10];
  const float* gamma = (const float*)d_in[11];
  const float* beta = (const float*)d_in[12];
  float* out = (float*)d_out;

  char* p = (char*)d_ws;
  auto carve = [&](size_t bytes) -> char* {
    char* r = p;
    p += (bytes + 255) & ~(size_t)255;
    return r;
  };
  u16* hid_bf = (u16*)carve((size_t)4096 * 1024 * 2);
  u16* rel_bf = (u16*)carve((size_t)512 * 1024 * 2);
  u16* wqkv_bf = (u16*)carve((size_t)3072 * 1024 * 2);
  u16* wo_bf = (u16*)carve((size_t)1024 * 1024 * 2);
  u16* qkv_rm = (u16*)carve((size_t)4096 * 3072 * 2);   // [B*S, 3072] bf16
  // pos_rm before Vtb: flash window B-reads may overrun by <=15 rows (never gathered)
  u16* pos_rm = (u16*)carve((size_t)512 * 2048 * 2);    // [512, 2048] bf16
  u16* Vtb = (u16*)carve((size_t)BATCH * NH * HD * S_LEN * 2);
  u16* ctx = (u16*)carve((size_t)4096 * 1024 * 2);
  float* tmp = (float*)carve((size_t)4096 * 1024 * 4);
  float* biascat = (float*)carve((size_t)3072 * 4);
  int* tab = (int*)carve((size_t)2047 * 4);

  const float inv_scale = 1.0f / sqrtf(192.0f);
  const float sc2 = inv_scale * 1.44269504089f;  // fold log2(e) for exp2f

  prep_kernel<<<dim3(16), dim3(256), 0, stream>>>(tab, bq, bk, bv, biascat);
  cast_all<<<dim3(8704), dim3(256), 0, stream>>>(hidden, rel, Wq, Wk, Wv, Wo, hid_bf,
                                                 rel_bf, wqkv_bf, wo_bf);

  // QKV: [4096,3072,1024] -> row-major bf16 (+bias)
  mgemm<<<dim3(24, 32), 256, 0, stream>>>(hid_bf, wqkv_bf, biascat, nullptr, qkv_rm,
                                          4096, 3072, 1024, 1);
  // pos projections: [512,2048,1024] over [Wq;Wk] -> row-major bf16 (+bias)
  mgemm<<<dim3(16, 4), 256, 0, stream>>>(rel_bf, wqkv_bf, biascat, nullptr, pos_rm,
                                         512, 2048, 1024, 1);
  // V -> [B,H,64,S]
  vtrans<<<dim3(16, NH, BATCH), 256, 0, stream>>>(qkv_rm, Vtb);

  // fused flash attention, LDS-staged K/V + on-chip bias recompute, 3 blocks/CU
  flash_mfma<<<dim3(16, NH, BATCH), 256, 0, stream>>>(qkv_rm, Vtb, pos_rm, tab, ctx, sc2);

  // out-proj + bias + residual (f32), then LN
  mgemm<<<dim3(8, 32), 256, 0, stream>>>(ctx, wo_bf, bo, hidden, tmp, 4096, 1024, 1024, 0);
  ln_kernel<<<dim3(4096), 256, 0, stream>>>(tmp, gamma, beta, out);
}

// Round 9
// 384.081 us; speedup vs baseline: 1.1991x; 1.0490x over previous
//
#include <hip/hip_runtime.h>
#include <math.h>

#define S_LEN 1024
#define DMODEL 1024
#define NH 16
#define HD 64
#define P2 512
#define BATCH 4

typedef unsigned short u16;
typedef __attribute__((ext_vector_type(8))) short short8;
typedef __attribute__((ext_vector_type(4))) float floatx4;

__device__ __forceinline__ u16 f2bf(float f) {
  unsigned u = __float_as_uint(f);
  unsigned r = u + 0x7FFFu + ((u >> 16) & 1u);
  return (u16)(r >> 16);
}
__device__ __forceinline__ float bf2f(u16 v) {
  return __uint_as_float(((unsigned)v) << 16);
}
__device__ __forceinline__ unsigned pk2bf(float a, float b) {
#if __has_builtin(__builtin_amdgcn_cvt_pk_bf16_f32)
  typedef __attribute__((ext_vector_type(2))) __bf16 bf2v;
  bf2v t = __builtin_amdgcn_cvt_pk_bf16_f32(a, b);
  return *(unsigned*)&t;
#else
  return (unsigned)f2bf(a) | ((unsigned)f2bf(b) << 16);
#endif
}
// async global->LDS, 16B per lane; lds dest = wave-uniform base + lane*16
__device__ __forceinline__ void gl_lds16(const void* g, void* l) {
  __builtin_amdgcn_global_load_lds(
      (const __attribute__((address_space(1))) void*)g,
      (__attribute__((address_space(3))) void*)l, 16, 0, 0);
}

// ---------------- prep: tab + concatenated bias ----------------
__global__ void prep_kernel(int* __restrict__ tab, const float* __restrict__ bq,
                            const float* __restrict__ bk, const float* __restrict__ bv,
                            float* __restrict__ biascat) {
  int t = blockIdx.x * blockDim.x + threadIdx.x;
  if (t < 2 * S_LEN - 1) {
    int rel = t - (S_LEN - 1);
    const int mid = 128;
    float abspos = (rel < mid && rel > -mid) ? (float)(mid - 1) : fabsf((float)rel);
    float bucket;
    if (abspos <= (float)mid) {
      bucket = (float)rel;
    } else {
      float den = (float)log(3.9921875);
      float lp = ceilf(logf(abspos / 128.0f) / den * 127.0f) + 128.0f;
      bucket = (rel > 0) ? lp : -lp;
    }
    int idx = (int)bucket + 256;
    idx = idx < 0 ? 0 : (idx > P2 - 1 ? P2 - 1 : idx);
    tab[t] = idx;
  }
  if (t < 3072) biascat[t] = t < 1024 ? bq[t] : (t < 2048 ? bk[t - 1024] : bv[t - 2048]);
}

// ---------------- single fused f32->bf16 cast over all inputs ----------------
__global__ __launch_bounds__(256) void cast_all(
    const float* __restrict__ h, const float* __restrict__ r,
    const float* __restrict__ wq, const float* __restrict__ wk,
    const float* __restrict__ wv, const float* __restrict__ wo,
    u16* __restrict__ hb, u16* __restrict__ rb,
    u16* __restrict__ wqkvb, u16* __restrict__ wob) {
  int b = blockIdx.x;
  const float* src;
  u16* dst;
  int off;
  if (b < 4096) { src = h; dst = hb; off = b; }
  else if (b < 4608) { src = r; dst = rb; off = b - 4096; }
  else if (b < 5632) { src = wq; dst = wqkvb; off = b - 4608; }
  else if (b < 6656) { src = wk; dst = wqkvb + 1024 * 1024; off = b - 5632; }
  else if (b < 7680) { src = wv; dst = wqkvb + 2 * 1024 * 1024; off = b - 6656; }
  else { src = wo; dst = wob; off = b - 7680; }
  long i = (long)off * 1024 + (threadIdx.x << 2);
  float4 v = *(const float4*)(src + i);
  uint2 o;
  o.x = pk2bf(v.x, v.y);
  o.y = pk2bf(v.z, v.w);
  *(uint2*)(dst + i) = o;
}

// ---------------- bf16 MFMA NT GEMM, 128x128 tile, BK=32 ----------------
// mode 0: f32 out + bias + resid (out-proj).
// mode 1: bf16 row-major out + bias, LDS-transposed coalesced epilogue.
__global__ __launch_bounds__(256) void mgemm(
    const u16* __restrict__ A, const u16* __restrict__ Bw,
    const float* __restrict__ b0, const float* __restrict__ resid,
    void* out0, int M, int N, int K, int mode) {
  __shared__ u16 Stage[2][128 * 32];
  u16* Al = Stage[0];
  u16* Bl = Stage[1];
  const int tid = threadIdx.x;
  const int wave = tid >> 6, lane = tid & 63;
  const int quad = lane >> 4, l16 = lane & 15;
  const int m0 = blockIdx.y * 128, n0 = blockIdx.x * 128;

  const floatx4 fzero = {0.f, 0.f, 0.f, 0.f};
  floatx4 acc[4][4];
#pragma unroll
  for (int mi = 0; mi < 4; ++mi)
#pragma unroll
    for (int ni = 0; ni < 4; ++ni) acc[mi][ni] = fzero;

  const int wm = (wave & 1) * 64, wn = (wave >> 1) * 64;

  for (int k0 = 0; k0 < K; k0 += 32) {
#pragma unroll
    for (int i = 0; i < 2; ++i) {
      int ch = i * 256 + wave * 64 + lane;
      int row = ch >> 2, c = ch & 3;
      gl_lds16(A + (long)(m0 + row) * K + k0 + c * 8, Al + (i * 256 + wave * 64) * 8);
      gl_lds16(Bw + (long)(n0 + row) * K + k0 + c * 8, Bl + (i * 256 + wave * 64) * 8);
    }
    __syncthreads();
    short8 af[4], bf[4];
#pragma unroll
    for (int t = 0; t < 4; ++t) {
      af[t] = *(const short8*)(Al + (wm + t * 16 + l16) * 32 + quad * 8);
      bf[t] = *(const short8*)(Bl + (wn + t * 16 + l16) * 32 + quad * 8);
    }
#pragma unroll
    for (int mi = 0; mi < 4; ++mi)
#pragma unroll
      for (int ni = 0; ni < 4; ++ni)
        acc[mi][ni] =
            __builtin_amdgcn_mfma_f32_16x16x32_bf16(af[mi], bf[ni], acc[mi][ni], 0, 0, 0);
    __syncthreads();
  }

  if (mode == 0) {
    float* o = (float*)out0;
#pragma unroll
    for (int mi = 0; mi < 4; ++mi)
#pragma unroll
      for (int ni = 0; ni < 4; ++ni) {
        int n = n0 + wn + ni * 16 + l16;
#pragma unroll
        for (int r = 0; r < 4; ++r) {
          int m = m0 + wm + mi * 16 + quad * 4 + r;
          o[(long)m * N + n] = acc[mi][ni][r] + b0[n] + resid[(long)m * N + n];
        }
      }
  } else {
    u16* o = (u16*)out0;
    u16* T = &Stage[0][0];  // 32 x 132 u16 = 8448 B
    const int wp = wave & 1;
    float biasv[4];
#pragma unroll
    for (int ni = 0; ni < 4; ++ni) biasv[ni] = b0[n0 + wn + ni * 16 + l16];
#pragma unroll
    for (int p = 0; p < 4; ++p) {
#pragma unroll
      for (int ni = 0; ni < 4; ++ni) {
        int cl = wn + ni * 16 + l16;
#pragma unroll
        for (int r = 0; r < 4; ++r)
          T[(wp * 16 + quad * 4 + r) * 132 + cl] = f2bf(acc[p][ni][r] + biasv[ni]);
      }
      __syncthreads();
#pragma unroll
      for (int u = 0; u < 4; ++u) {
        int ch = u * 256 + tid;
        int row = ch >> 5, c4 = (ch & 31) << 2;
        int gr = m0 + (row >> 4) * 64 + p * 16 + (row & 15);
        *(ushort4*)(o + (long)gr * N + n0 + c4) = *(const ushort4*)(T + row * 132 + c4);
      }
      if (p < 3) __syncthreads();
    }
  }
}

// ---------------- V transpose: qkv_rm V-part -> Vt [B,H,64,S] ----------------
__global__ __launch_bounds__(256) void vtrans(const u16* __restrict__ qkv,
                                              u16* __restrict__ Vt) {
  __shared__ u16 tile[64][68];
  const int s0 = blockIdx.x * 64, h = blockIdx.y, b = blockIdx.z;
  const int t = threadIdx.x;
  const int r16 = t >> 4, c4 = (t & 15) << 2;
  const u16* src = qkv + ((long)(b * S_LEN + s0)) * 3072 + 2048 + h * HD;
#pragma unroll
  for (int i = 0; i < 4; ++i) {
    int row = i * 16 + r16;
    ushort4 v = *(const ushort4*)(src + (long)row * 3072 + c4);
    *(ushort4*)&tile[row][c4] = v;
  }
  __syncthreads();
  u16* dst = Vt + ((long)(b * NH + h) * HD) * S_LEN + s0;
#pragma unroll
  for (int i = 0; i < 4; ++i) {
    int dd = i * 16 + r16;
    ushort4 o;
    o.x = tile[c4 + 0][dd]; o.y = tile[c4 + 1][dd];
    o.z = tile[c4 + 2][dd]; o.w = tile[c4 + 3][dd];
    *(ushort4*)(dst + (long)dd * S_LEN + c4) = o;
  }
}

// ---------------- MFMA flash attention (r5 structure + XCD-affinity swizzle) ----
// 1-D grid, id = g + 64*qi (g = b*16+h, qi = q-block). All 16 q-blocks of a group
// satisfy id % 8 == g % 8 -> same XCD under round-robin dispatch, so the group's
// K/V (256 KB) stays L2-resident and is re-fetched from HBM only once.
__global__ __launch_bounds__(256, 2) void flash_mfma(
    const u16* __restrict__ qkv, const u16* __restrict__ Vt,
    const u16* __restrict__ pos, const int* __restrict__ tab,
    u16* __restrict__ ctx, float inv_scale) {
  __shared__ u16 Qs[64 * 64];
  __shared__ u16 Ks[64 * 64];
  __shared__ u16 Vs[64 * 64];     // [dd][k]
  __shared__ u16 CsT[128 * 68];   // Gq^T [off][qloc]
  __shared__ u16 DsT[128 * 68];   // Gk^T [off][kloc]
  __shared__ u16 Ps[4][16 * 72];  // per-wave P strip
  __shared__ u16 offL[128];

  const int tid = threadIdx.x;
  const int wave = tid >> 6, lane = tid & 63;
  const int quad = lane >> 4, l16 = lane & 15;
  const int id = blockIdx.x;
  const int g = id & 63, qi = id >> 6;
  const int b = g >> 4, h = g & 15, q0 = qi * 64;

  const u16* Qg = qkv + ((long)(b * S_LEN + q0)) * 3072 + h * HD;
  const u16* Kg = qkv + ((long)(b * S_LEN)) * 3072 + 1024 + h * HD;
  const u16* Vg = Vt + ((long)(b * NH + h) * HD) * S_LEN;
  const u16* posq_g = pos + h * HD;         // [512,2048] rows, Wq cols
  const u16* posk_g = pos + 1024 + h * HD;  // Wk cols

  // stage Q
#pragma unroll
  for (int i = 0; i < 2; ++i) {
    int ch = i * 256 + wave * 64 + lane;
    int row = ch >> 3, c = ch & 7;
    gl_lds16(Qg + (long)row * 3072 + c * 8, Qs + (i * 256 + wave * 64) * 8);
  }
  __syncthreads();
  short8 aq[4][2];
#pragma unroll
  for (int mi = 0; mi < 4; ++mi)
#pragma unroll
    for (int kk = 0; kk < 2; ++kk)
      aq[mi][kk] = *(const short8*)(Qs + (mi * 16 + l16) * 64 + kk * 32 + quad * 8);

  const floatx4 fzero = {0.f, 0.f, 0.f, 0.f};
  floatx4 acc[4];
#pragma unroll
  for (int ni = 0; ni < 4; ++ni) acc[ni] = fzero;
  float l_i[4] = {0.f, 0.f, 0.f, 0.f};

  u16* Pw = &Ps[wave][0];
  const int qb4 = wave * 16 + quad * 4;

  for (int k0 = 0; k0 < S_LEN; k0 += 64) {
    const int dmin = q0 - k0 - 63;
    const int base = tab[dmin + 1023];
    const int w = tab[dmin + 1023 + 126] - base + 1;  // monotone => 1..127
    const int nsl = (w + 15) >> 4;
    if (tid < 127) offL[tid] = (u16)(tab[dmin + 1023 + tid] - base);
#pragma unroll
    for (int i = 0; i < 2; ++i) {
      int ch = i * 256 + wave * 64 + lane;
      int row = ch >> 3, c = ch & 7;
      gl_lds16(Kg + (long)(k0 + row) * 3072 + c * 8, Ks + (i * 256 + wave * 64) * 8);
      gl_lds16(Vg + (long)row * S_LEN + k0 + c * 8, Vs + (i * 256 + wave * 64) * 8);
    }
    __syncthreads();  // #1: K,V staged; offL visible

    // K fragments once: serve Gk-A and QK-B
    short8 ak[4][2];
#pragma unroll
    for (int ni = 0; ni < 4; ++ni)
#pragma unroll
      for (int kk = 0; kk < 2; ++kk)
        ak[ni][kk] = *(const short8*)(Ks + (ni * 16 + l16) * 64 + kk * 32 + quad * 8);

    // ---- Gq slices (wave-strided) -> CsT ----
    for (int sl = wave; sl < nsl; sl += 4) {
      floatx4 g4[4];
#pragma unroll
      for (int mi = 0; mi < 4; ++mi) g4[mi] = fzero;
      int wrow = base + sl * 16 + l16;
#pragma unroll
      for (int kk = 0; kk < 2; ++kk) {
        short8 bp = *(const short8*)(posk_g + (long)wrow * 2048 + kk * 32 + quad * 8);
#pragma unroll
        for (int mi = 0; mi < 4; ++mi)
          g4[mi] = __builtin_amdgcn_mfma_f32_16x16x32_bf16(aq[mi][kk], bp, g4[mi], 0, 0, 0);
      }
#pragma unroll
      for (int mi = 0; mi < 4; ++mi) {
        uint2 t;
        t.x = pk2bf(g4[mi][0], g4[mi][1]);
        t.y = pk2bf(g4[mi][2], g4[mi][3]);
        *(uint2*)(CsT + (sl * 16 + l16) * 68 + mi * 16 + quad * 4) = t;
      }
    }
    // ---- Gk slices -> DsT ----
    for (int sl = wave; sl < nsl; sl += 4) {
      floatx4 g4[4];
#pragma unroll
      for (int mi = 0; mi < 4; ++mi) g4[mi] = fzero;
      int wrow = base + sl * 16 + l16;
#pragma unroll
      for (int kk = 0; kk < 2; ++kk) {
        short8 bp = *(const short8*)(posq_g + (long)wrow * 2048 + kk * 32 + quad * 8);
#pragma unroll
        for (int mi = 0; mi < 4; ++mi)
          g4[mi] = __builtin_amdgcn_mfma_f32_16x16x32_bf16(ak[mi][kk], bp, g4[mi], 0, 0, 0);
      }
#pragma unroll
      for (int mi = 0; mi < 4; ++mi) {
        uint2 t;
        t.x = pk2bf(g4[mi][0], g4[mi][1]);
        t.y = pk2bf(g4[mi][2], g4[mi][3]);
        *(uint2*)(DsT + (sl * 16 + l16) * 68 + mi * 16 + quad * 4) = t;
      }
    }

    // ---- QK^T for this wave's q-strip (B-operands = ak) ----
    floatx4 s[4];
#pragma unroll
    for (int ni = 0; ni < 4; ++ni) s[ni] = fzero;
#pragma unroll
    for (int kk = 0; kk < 2; ++kk)
#pragma unroll
      for (int ni = 0; ni < 4; ++ni)
        s[ni] = __builtin_amdgcn_mfma_f32_16x16x32_bf16(aq[wave][kk], ak[ni][kk],
                                                        s[ni], 0, 0, 0);

    __syncthreads();  // #2: CsT/DsT complete

    float pv[4][4];
#pragma unroll
    for (int ni = 0; ni < 4; ++ni) {
      int kloc = ni * 16 + l16;
#pragma unroll
      for (int r = 0; r < 4; ++r) {
        int off = offL[qb4 + r - kloc + 63];
        float v = (s[ni][r] + bf2f(CsT[off * 68 + qb4 + r]) +
                   bf2f(DsT[off * 68 + kloc])) * inv_scale;
        pv[ni][r] = __expf(v);
      }
    }
#pragma unroll
    for (int r = 0; r < 4; ++r) {
      float rs = pv[0][r] + pv[1][r] + pv[2][r] + pv[3][r];
      rs += __shfl_xor(rs, 1);
      rs += __shfl_xor(rs, 2);
      rs += __shfl_xor(rs, 4);
      rs += __shfl_xor(rs, 8);
      l_i[r] += rs;
    }
    // P: D-layout -> A-layout via per-wave strip
#pragma unroll
    for (int ni = 0; ni < 4; ++ni)
#pragma unroll
      for (int r = 0; r < 4; ++r)
        Pw[(quad * 4 + r) * 72 + ni * 16 + l16] = f2bf(pv[ni][r]);

#pragma unroll
    for (int kk = 0; kk < 2; ++kk) {
      short8 ap = *(const short8*)(Pw + l16 * 72 + kk * 32 + quad * 8);
#pragma unroll
      for (int ni = 0; ni < 4; ++ni) {
        short8 vv = *(const short8*)(Vs + (ni * 16 + l16) * 64 + kk * 32 + quad * 8);
        acc[ni] = __builtin_amdgcn_mfma_f32_16x16x32_bf16(ap, vv, acc[ni], 0, 0, 0);
      }
    }
    __syncthreads();  // #3: all reads done before next tile overwrites
  }

#pragma unroll
  for (int ni = 0; ni < 4; ++ni) {
    int dd = ni * 16 + l16;
#pragma unroll
    for (int r = 0; r < 4; ++r) {
      int qrow = q0 + qb4 + r;
      ctx[((long)(b * S_LEN) + qrow) * DMODEL + h * HD + dd] = f2bf(acc[ni][r] / l_i[r]);
    }
  }
}

// ---------------- LayerNorm over rows of 1024 ----------------
__global__ __launch_bounds__(256) void ln_kernel(
    const float* __restrict__ x, const float* __restrict__ gamma,
    const float* __restrict__ beta, float* __restrict__ out) {
  const int row = blockIdx.x;
  const int tid = threadIdx.x;
  const float* xr = x + (long)row * DMODEL;
  float4 v = *(const float4*)(xr + (tid << 2));
  float s = v.x + v.y + v.z + v.w;
#pragma unroll
  for (int off = 32; off; off >>= 1) s += __shfl_xor(s, off);
  __shared__ float red[4];
  if ((tid & 63) == 0) red[tid >> 6] = s;
  __syncthreads();
  float mu = (red[0] + red[1] + red[2] + red[3]) * (1.0f / DMODEL);
  float dx0 = v.x - mu, dx1 = v.y - mu, dx2 = v.z - mu, dx3 = v.w - mu;
  float sq = dx0 * dx0 + dx1 * dx1 + dx2 * dx2 + dx3 * dx3;
#pragma unroll
  for (int off = 32; off; off >>= 1) sq += __shfl_xor(sq, off);
  __syncthreads();
  if ((tid & 63) == 0) red[tid >> 6] = sq;
  __syncthreads();
  float var = (red[0] + red[1] + red[2] + red[3]) * (1.0f / DMODEL);
  float rstd = 1.0f / sqrtf(var + 1e-7f);
  float4 g = *(const float4*)(gamma + (tid << 2));
  float4 be = *(const float4*)(beta + (tid << 2));
  float4 o = make_float4(dx0 * rstd * g.x + be.x, dx1 * rstd * g.y + be.y,
                         dx2 * rstd * g.z + be.z, dx3 * rstd * g.w + be.w);
  *(float4*)(out + (long)row * DMODEL + (tid << 2)) = o;
}

extern "C" void kernel_launch(void* const* d_in, const int* in_sizes, int n_in,
                              void* d_out, int out_size, void* d_ws, size_t ws_size,
                              hipStream_t stream) {
  (void)in_sizes; (void)n_in; (void)out_size; (void)ws_size;
  const float* hidden = (const float*)d_in[0];
  const float* rel = (const float*)d_in[2];
  const float* Wq = (const float*)d_in[3];
  const float* bq = (const float*)d_in[4];
  const float* Wk = (const float*)d_in[5];
  const float* bk = (const float*)d_in[6];
  const float* Wv = (const float*)d_in[7];
  const float* bv = (const float*)d_in[8];
  const float* Wo = (const float*)d_in[9];
  const float* bo = (const float*)d_in[10];
  const float* gamma = (const float*)d_in[11];
  const float* beta = (const float*)d_in[12];
  float* out = (float*)d_out;

  char* p = (char*)d_ws;
  auto carve = [&](size_t bytes) -> char* {
    char* r = p;
    p += (bytes + 255) & ~(size_t)255;
    return r;
  };
  u16* hid_bf = (u16*)carve((size_t)4096 * 1024 * 2);
  u16* rel_bf = (u16*)carve((size_t)512 * 1024 * 2);
  u16* wqkv_bf = (u16*)carve((size_t)3072 * 1024 * 2);
  u16* wo_bf = (u16*)carve((size_t)1024 * 1024 * 2);
  u16* qkv_rm = (u16*)carve((size_t)4096 * 3072 * 2);   // [B*S, 3072] bf16
  // pos_rm before Vtb: flash window B-reads may overrun by <=15 rows (never gathered)
  u16* pos_rm = (u16*)carve((size_t)512 * 2048 * 2);    // [512, 2048] bf16
  u16* Vtb = (u16*)carve((size_t)BATCH * NH * HD * S_LEN * 2);
  u16* ctx = (u16*)carve((size_t)4096 * 1024 * 2);
  float* tmp = (float*)carve((size_t)4096 * 1024 * 4);
  float* biascat = (float*)carve((size_t)3072 * 4);
  int* tab = (int*)carve((size_t)2047 * 4);

  const float inv_scale = 1.0f / sqrtf(192.0f);

  prep_kernel<<<dim3(16), dim3(256), 0, stream>>>(tab, bq, bk, bv, biascat);
  cast_all<<<dim3(8704), dim3(256), 0, stream>>>(hidden, rel, Wq, Wk, Wv, Wo, hid_bf,
                                                 rel_bf, wqkv_bf, wo_bf);

  // QKV: [4096,3072,1024] -> row-major bf16 (+bias)
  mgemm<<<dim3(24, 32), 256, 0, stream>>>(hid_bf, wqkv_bf, biascat, nullptr, qkv_rm,
                                          4096, 3072, 1024, 1);
  // pos projections: [512,2048,1024] over [Wq;Wk] -> row-major bf16 (+bias)
  mgemm<<<dim3(16, 4), 256, 0, stream>>>(rel_bf, wqkv_bf, biascat, nullptr, pos_rm,
                                         512, 2048, 1024, 1);
  // V -> [B,H,64,S]
  vtrans<<<dim3(16, NH, BATCH), 256, 0, stream>>>(qkv_rm, Vtb);

  // fused flash attention, r5 structure + XCD-affinity swizzle (1-D grid)
  flash_mfma<<<dim3(1024), 256, 0, stream>>>(qkv_rm, Vtb, pos_rm, tab, ctx, inv_scale);

  // out-proj + bias + residual (f32), then LN
  mgemm<<<dim3(8, 32), 256, 0, stream>>>(ctx, wo_bf, bo, hidden, tmp, 4096, 1024, 1024, 0);
  ln_kernel<<<dim3(4096), 256, 0, stream>>>(tmp, gamma, beta, out);
}